// Round 3
// baseline (980.128 us; speedup 1.0000x reference)
//
#include <hip/hip_runtime.h>
#include <hip/hip_bf16.h>
#include <math.h>

typedef __bf16 bf16_t;
typedef __bf16 bf16x8 __attribute__((ext_vector_type(8)));
typedef float f32x4 __attribute__((ext_vector_type(4)));

#define T_DIM 2048
#define C_DIM 2048
#define NH 16
#define HS 128
#define NLQ 1536
#define NLKV 512
#define DHR 64
#define QKD 192  // HS + DHR

// ---------------------------------------------------------------- dtype detect
__global__ void detect_k(const bf16_t* __restrict__ x, int* __restrict__ flag) {
  int bad = 0;
  for (int i = threadIdx.x; i < 256; i += 64) {
    float v = (float)x[i];
    if (!(fabsf(v) < 1.0e6f)) bad = 1;  // catches NaN too
  }
  unsigned long long m = __ballot(bad);
  if (threadIdx.x == 0) *flag = (m != 0ull) ? 1 : 0;
}

__global__ void convert_k(const void* __restrict__ in, bf16_t* __restrict__ out,
                          int n, const int* __restrict__ flag) {
  int i = blockIdx.x * blockDim.x + threadIdx.x;
  if (i >= n) return;
  if (*flag) out[i] = (bf16_t)((const float*)in)[i];
  else       out[i] = ((const bf16_t*)in)[i];
}

// ---------------------------------------------------------------- transpose (dtype-flex in)
__global__ void transpose_k(const void* __restrict__ in, bf16_t* __restrict__ out,
                            int R, int C, const int* __restrict__ flag) {
  __shared__ bf16_t tile[32][33];
  const int f32 = *flag;
  int bx = blockIdx.x * 32, by = blockIdx.y * 32;
  int tx = threadIdx.x, ty = threadIdx.y;
  for (int i = ty; i < 32; i += 8) {
    int r = by + i, c = bx + tx;
    if (r < R && c < C) {
      size_t idx = (size_t)r * C + c;
      tile[i][tx] = f32 ? (bf16_t)((const float*)in)[idx] : ((const bf16_t*)in)[idx];
    }
  }
  __syncthreads();
  for (int i = ty; i < 32; i += 8) {
    int r = bx + i, c = by + tx;  // out[r][c] = in[c][r]
    if (r < C && c < R) out[(size_t)r * R + c] = tile[tx][i];
  }
}

// ---------------------------------------------------------------- GEMM  C = A @ B^T
// amode/bmode: 0 = operand is always bf16 (workspace); 1 = raw input, dtype per *flag.
#define BM 128
#define BN 128
#define BK 32
#define APITCH 40

__device__ __forceinline__ bf16x8 load8(const void* p, size_t off, int f32) {
  if (f32) {
    const float* pf = (const float*)p + off;
    f32x4 lo = *(const f32x4*)pf;
    f32x4 hi = *(const f32x4*)(pf + 4);
    bf16x8 v;
#pragma unroll
    for (int j = 0; j < 4; ++j) { v[j] = (bf16_t)lo[j]; v[j + 4] = (bf16_t)hi[j]; }
    return v;
  }
  return *(const bf16x8*)((const bf16_t*)p + off);
}

__global__ __launch_bounds__(256) void gemm_nt(const void* __restrict__ A,
                                               const void* __restrict__ B,
                                               bf16_t* __restrict__ Cm,
                                               int M, int N, int K,
                                               int lda, int ldb, int ldc,
                                               const int* __restrict__ flag,
                                               int amode, int bmode) {
  __shared__ bf16_t As[BM * APITCH];
  __shared__ bf16_t Bs[BN * APITCH];
  const int tid = threadIdx.x;
  const int lane = tid & 63;
  const int wave = tid >> 6;
  const int l16 = lane & 15, quad = lane >> 4;
  const int bm = blockIdx.x * BM, bn = blockIdx.y * BN;
  const int wm = (wave >> 1) * 64, wn = (wave & 1) * 64;
  const int fl = *flag;
  const int af32 = amode ? fl : 0;
  const int bf32 = bmode ? fl : 0;
  f32x4 acc[4][4] = {};

  for (int k0 = 0; k0 < K; k0 += BK) {
    __syncthreads();
#pragma unroll
    for (int r = 0; r < 2; ++r) {
      int idx = r * 256 + tid;
      int row = idx >> 2;
      int col = (idx & 3) * 8;
      int ar = bm + row; if (ar > M - 1) ar = M - 1;
      bf16x8 va = load8(A, (size_t)ar * lda + k0 + col, af32);
      *(bf16x8*)(As + row * APITCH + col) = va;
      int br = bn + row; if (br > N - 1) br = N - 1;
      bf16x8 vb = load8(B, (size_t)br * ldb + k0 + col, bf32);
      *(bf16x8*)(Bs + row * APITCH + col) = vb;
    }
    __syncthreads();
    bf16x8 af[4], bfr[4];
#pragma unroll
    for (int i = 0; i < 4; ++i)
      af[i] = *(const bf16x8*)(As + (wm + i * 16 + l16) * APITCH + quad * 8);
#pragma unroll
    for (int j = 0; j < 4; ++j)
      bfr[j] = *(const bf16x8*)(Bs + (wn + j * 16 + l16) * APITCH + quad * 8);
#pragma unroll
    for (int i = 0; i < 4; ++i)
#pragma unroll
      for (int j = 0; j < 4; ++j)
        acc[i][j] = __builtin_amdgcn_mfma_f32_16x16x32_bf16(af[i], bfr[j], acc[i][j], 0, 0, 0);
  }
#pragma unroll
  for (int i = 0; i < 4; ++i)
#pragma unroll
    for (int j = 0; j < 4; ++j)
#pragma unroll
      for (int r = 0; r < 4; ++r) {
        int gm = bm + wm + i * 16 + quad * 4 + r;
        int gn = bn + wn + j * 16 + l16;
        if (gm < M && gn < N) Cm[(size_t)gm * ldc + gn] = (bf16_t)acc[i][j][r];
      }
}

// ---------------------------------------------------------------- pack + rope
__global__ void pack_q_k(const bf16_t* __restrict__ qup, const bf16_t* __restrict__ qr,
                         const bf16_t* __restrict__ fc, const bf16_t* __restrict__ fs,
                         bf16_t* __restrict__ Qp) {
  int idx = blockIdx.x * blockDim.x + threadIdx.x;
  if (idx >= NH * T_DIM * 96) return;
  int j = idx % 96;
  int t = (idx / 96) % T_DIM;
  int h = idx / (96 * T_DIM);
  const float scale = 0.07216878364870323f;  // 1/sqrt(HS+DHR)
  bf16_t* out = Qp + ((size_t)h * T_DIM + t) * QKD;
  if (j < 64) {
    float a = (float)qup[(size_t)t * C_DIM + h * HS + 2 * j];
    float b = (float)qup[(size_t)t * C_DIM + h * HS + 2 * j + 1];
    out[2 * j] = (bf16_t)(a * scale);
    out[2 * j + 1] = (bf16_t)(b * scale);
  } else {
    int i = j - 64;
    float re = (float)qr[(size_t)t * (NH * DHR) + h * DHR + 2 * i];
    float im = (float)qr[(size_t)t * (NH * DHR) + h * DHR + 2 * i + 1];
    float c = (float)fc[t * 32 + i], s = (float)fs[t * 32 + i];
    out[HS + 2 * i] = (bf16_t)((re * c - im * s) * scale);
    out[HS + 2 * i + 1] = (bf16_t)((re * s + im * c) * scale);
  }
}

__global__ void pack_k_k(const bf16_t* __restrict__ khead, const bf16_t* __restrict__ kr,
                         const bf16_t* __restrict__ fc, const bf16_t* __restrict__ fs,
                         bf16_t* __restrict__ Kp) {
  int idx = blockIdx.x * blockDim.x + threadIdx.x;
  if (idx >= NH * T_DIM * 96) return;
  int j = idx % 96;
  int t = (idx / 96) % T_DIM;
  int h = idx / (96 * T_DIM);
  bf16_t* out = Kp + ((size_t)h * T_DIM + t) * QKD;
  if (j < 64) {
    out[2 * j] = khead[(size_t)t * C_DIM + h * HS + 2 * j];
    out[2 * j + 1] = khead[(size_t)t * C_DIM + h * HS + 2 * j + 1];
  } else {
    int i = j - 64;
    float re = (float)kr[(size_t)t * DHR + 2 * i];
    float im = (float)kr[(size_t)t * DHR + 2 * i + 1];
    float c = (float)fc[t * 32 + i], s = (float)fs[t * 32 + i];
    out[HS + 2 * i] = (bf16_t)(re * c - im * s);
    out[HS + 2 * i + 1] = (bf16_t)(re * s + im * c);
  }
}

// ---------------------------------------------------------------- flash attention
// VT is pre-transposed: VT[h*HS + d][t]  (row stride T_DIM)
#define FBM 64
#define FBN 64
#define KPITCH 200
#define VPITCH 72
#define PPITCH 72

__global__ __launch_bounds__(256) void flash_k(const bf16_t* __restrict__ Qp,
                                               const bf16_t* __restrict__ Kp,
                                               const bf16_t* __restrict__ VT,
                                               void* __restrict__ Y,
                                               const int* __restrict__ flag) {
  __shared__ bf16_t Ksm[FBN * KPITCH];
  __shared__ bf16_t Vtsm[HS * VPITCH];
  __shared__ bf16_t Psm[4][16 * PPITCH];
  const int tid = threadIdx.x;
  const int lane = tid & 63, wave = tid >> 6;
  const int l16 = lane & 15, quad = lane >> 4;
  const int h = blockIdx.y;
  const int qtile = (gridDim.x - 1) - blockIdx.x;  // longest-first dispatch
  const int qb = qtile * FBM;
  const int f32out = *flag;

  bf16x8 aq[6];
  const bf16_t* qbase = Qp + ((size_t)h * T_DIM + qb + wave * 16 + l16) * QKD;
#pragma unroll
  for (int c = 0; c < 6; ++c) aq[c] = *(const bf16x8*)(qbase + c * 32 + quad * 8);

  f32x4 o[8] = {};
  float m_i[4], l_i[4];
#pragma unroll
  for (int r = 0; r < 4; ++r) { m_i[r] = -3.0e38f; l_i[r] = 0.f; }

  for (int kt = 0; kt <= qtile; ++kt) {
    __syncthreads();
    {
      const bf16_t* kg = Kp + ((size_t)h * T_DIM + kt * FBN) * QKD;
#pragma unroll
      for (int i = 0; i < 6; ++i) {
        int idx = i * 256 + tid;  // 64 rows * 24 vec8
        int row = idx / 24, c8 = idx % 24;
        bf16x8 v = *(const bf16x8*)(kg + (size_t)row * QKD + c8 * 8);
        *(bf16x8*)(Ksm + row * KPITCH + c8 * 8) = v;
      }
      // V^T tile: rows d=0..127, cols s=0..63 — vectorized, conflict-free staging
      const bf16_t* vg = VT + (size_t)(h * HS) * T_DIM + kt * FBN;
#pragma unroll
      for (int i = 0; i < 4; ++i) {
        int idx = i * 256 + tid;  // 128 rows * 8 vec8
        int row = idx >> 3, c8 = idx & 7;
        bf16x8 v = *(const bf16x8*)(vg + (size_t)row * T_DIM + c8 * 8);
        *(bf16x8*)(Vtsm + row * VPITCH + c8 * 8) = v;
      }
    }
    __syncthreads();
    f32x4 sc[4] = {};
#pragma unroll
    for (int nt = 0; nt < 4; ++nt)
#pragma unroll
      for (int c = 0; c < 6; ++c) {
        bf16x8 bk = *(const bf16x8*)(Ksm + (nt * 16 + l16) * KPITCH + c * 32 + quad * 8);
        sc[nt] = __builtin_amdgcn_mfma_f32_16x16x32_bf16(aq[c], bk, sc[nt], 0, 0, 0);
      }
    if (kt == qtile) {
#pragma unroll
      for (int nt = 0; nt < 4; ++nt) {
        int s_loc = nt * 16 + l16;
#pragma unroll
        for (int r = 0; r < 4; ++r) {
          int t_loc = wave * 16 + quad * 4 + r;
          if (s_loc > t_loc) sc[nt][r] = -3.0e38f;
        }
      }
    }
    float p[4][4];
#pragma unroll
    for (int r = 0; r < 4; ++r) {
      float mx = fmaxf(fmaxf(sc[0][r], sc[1][r]), fmaxf(sc[2][r], sc[3][r]));
#pragma unroll
      for (int m = 1; m < 16; m <<= 1) mx = fmaxf(mx, __shfl_xor(mx, m, 64));
      float mn = fmaxf(m_i[r], mx);
      float alpha = exp2f((m_i[r] - mn) * 1.4426950408889634f);
      float rs = 0.f;
#pragma unroll
      for (int nt = 0; nt < 4; ++nt) {
        float pv = exp2f((sc[nt][r] - mn) * 1.4426950408889634f);
        p[nt][r] = pv;
        rs += pv;
      }
#pragma unroll
      for (int m = 1; m < 16; m <<= 1) rs += __shfl_xor(rs, m, 64);
      l_i[r] = l_i[r] * alpha + rs;
      m_i[r] = mn;
#pragma unroll
      for (int dt = 0; dt < 8; ++dt) o[dt][r] *= alpha;
    }
#pragma unroll
    for (int nt = 0; nt < 4; ++nt)
#pragma unroll
      for (int r = 0; r < 4; ++r)
        Psm[wave][(quad * 4 + r) * PPITCH + nt * 16 + l16] = (bf16_t)p[nt][r];
#pragma unroll
    for (int s2 = 0; s2 < 2; ++s2) {
      bf16x8 ap = *(const bf16x8*)(&Psm[wave][l16 * PPITCH + s2 * 32 + quad * 8]);
#pragma unroll
      for (int dt = 0; dt < 8; ++dt) {
        bf16x8 bv = *(const bf16x8*)(Vtsm + (dt * 16 + l16) * VPITCH + s2 * 32 + quad * 8);
        o[dt] = __builtin_amdgcn_mfma_f32_16x16x32_bf16(ap, bv, o[dt], 0, 0, 0);
      }
    }
  }
#pragma unroll
  for (int r = 0; r < 4; ++r) {
    float inv = 1.0f / l_i[r];
    int t = qb + wave * 16 + quad * 4 + r;
#pragma unroll
    for (int dt = 0; dt < 8; ++dt) {
      size_t oi = (size_t)t * C_DIM + h * HS + dt * 16 + l16;
      float val = o[dt][r] * inv;
      if (f32out) ((float*)Y)[oi] = val;
      else        ((bf16_t*)Y)[oi] = (bf16_t)val;
    }
  }
}

// ---------------------------------------------------------------- launch
extern "C" void kernel_launch(void* const* d_in, const int* in_sizes, int n_in,
                              void* d_out, int out_size, void* d_ws, size_t ws_size,
                              hipStream_t stream) {
  bf16_t* w = (bf16_t*)d_ws;
  int* flag = (int*)d_ws;  // first 4 bytes; buffers start at element 64

  // required: ~24.4M elements * 2B
  if (ws_size < (size_t)24379968 * 2 + 128) return;

  bf16_t* fcc    = w + 64;         // 65536
  bf16_t* fsc    = w + 65600;      // 65536
  bf16_t* c_q    = w + 131136;     // 3145728
  bf16_t* W_uq_t = w + 3276864;    // 3145728
  bf16_t* q_up   = w + 6422592;    // 4194304
  bf16_t* q_r    = w + 10616896;   // 2097152
  bf16_t* c_kv   = w + 12714048;   // 1048576
  bf16_t* k_head = w + 13762624;   // 4194304
  bf16_t* vhatT  = w + 17956928;   // 4194304
  bf16_t* W_uv_t = w + 22151232;   // 1048576
  bf16_t* Pt     = w + 23199808;   // 1048576
  bf16_t* k_r    = w + 24248384;   // 131072
  // aliases (lifetime-disjoint)
  bf16_t* Qpack = c_q;    // 6291456 over c_q+W_uq_t (both dead after q_r GEMM)
  bf16_t* Kpack = q_up;   // 6291456 over q_up+q_r (dead after pack_q_k)

  detect_k<<<1, 64, 0, stream>>>((const bf16_t*)d_in[0], flag);

  convert_k<<<(T_DIM * 32 + 255) / 256, 256, 0, stream>>>(d_in[1], fcc, T_DIM * 32, flag);
  convert_k<<<(T_DIM * 32 + 255) / 256, 256, 0, stream>>>(d_in[2], fsc, T_DIM * 32, flag);

  dim3 tb(32, 8);
  // W_uq flat (1536,2048) -> W_uq_t (2048,1536)
  transpose_k<<<dim3(64, 48), tb, 0, stream>>>(d_in[4], W_uq_t, 1536, 2048, flag);
  // W_uv (2048,512) -> W_uv_t (512,2048)
  transpose_k<<<dim3(16, 64), tb, 0, stream>>>(d_in[7], W_uv_t, 2048, 512, flag);

  // c_q = x @ W_dq^T          (2048,1536,K=2048)  raw,raw
  gemm_nt<<<dim3(16, 12), 256, 0, stream>>>(d_in[0], d_in[3], c_q, 2048, 1536, 2048, 2048, 2048, 1536, flag, 1, 1);
  // q_up = c_q @ W_uq_t^T     (2048,2048,K=1536)  ws,ws
  gemm_nt<<<dim3(16, 16), 256, 0, stream>>>(c_q, W_uq_t, q_up, 2048, 2048, 1536, 1536, 1536, 2048, flag, 0, 0);
  // q_r = c_q @ W_qr^T        (2048,1024,K=1536)  ws,raw
  gemm_nt<<<dim3(16, 8), 256, 0, stream>>>(c_q, d_in[8], q_r, 2048, 1024, 1536, 1536, 1536, 1024, flag, 0, 1);
  // c_kv = x @ W_dkv^T        (2048,512,K=2048)   raw,raw
  gemm_nt<<<dim3(16, 4), 256, 0, stream>>>(d_in[0], d_in[5], c_kv, 2048, 512, 2048, 2048, 2048, 512, flag, 1, 1);
  // k_r = x @ W_kr^T          (2048,64,K=2048)    raw,raw
  gemm_nt<<<dim3(16, 1), 256, 0, stream>>>(d_in[0], d_in[9], k_r, 2048, 64, 2048, 2048, 2048, 64, flag, 1, 1);
  // k_head = c_kv @ W_uk^T    (2048,2048,K=512)   ws,raw
  gemm_nt<<<dim3(16, 16), 256, 0, stream>>>(c_kv, d_in[6], k_head, 2048, 2048, 512, 512, 512, 2048, flag, 0, 1);
  // Pt = W_o @ W_uv_t^T       (2048,512,K=2048)   raw,ws
  gemm_nt<<<dim3(16, 4), 256, 0, stream>>>(d_in[10], W_uv_t, Pt, 2048, 512, 2048, 2048, 2048, 512, flag, 1, 0);
  // vhatT = Pt @ c_kv^T       (2048,2048,K=512)   ws,ws  — V^T directly, no transpose pass
  gemm_nt<<<dim3(16, 16), 256, 0, stream>>>(Pt, c_kv, vhatT, 2048, 2048, 512, 512, 512, 2048, flag, 0, 0);

  int pk = (NH * T_DIM * 96 + 255) / 256;
  pack_q_k<<<pk, 256, 0, stream>>>(q_up, q_r, fcc, fsc, Qpack);
  pack_k_k<<<pk, 256, 0, stream>>>(k_head, k_r, fcc, fsc, Kpack);

  flash_k<<<dim3(T_DIM / FBM, NH), 256, 0, stream>>>(Qpack, Kpack, vhatT, d_out, flag);
}

// Round 4
// 440.182 us; speedup vs baseline: 2.2266x; 2.2266x over previous
//
#include <hip/hip_runtime.h>
#include <hip/hip_bf16.h>
#include <math.h>

typedef __bf16 bf16_t;
typedef __bf16 bf16x8 __attribute__((ext_vector_type(8)));
typedef float f32x4 __attribute__((ext_vector_type(4)));

#define T_DIM 2048
#define C_DIM 2048
#define NH 16
#define HS 128
#define NLQ 1536
#define NLKV 512
#define DHR 64
#define QKD 192  // HS + DHR

// ---------------------------------------------------------------- dtype detect
__global__ void detect_k(const bf16_t* __restrict__ x, int* __restrict__ flag) {
  int bad = 0;
  for (int i = threadIdx.x; i < 256; i += 64) {
    float v = (float)x[i];
    if (!(fabsf(v) < 1.0e6f)) bad = 1;  // catches NaN too
  }
  unsigned long long m = __ballot(bad);
  if (threadIdx.x == 0) *flag = (m != 0ull) ? 1 : 0;
}

// ---------------------------------------------------------------- batched convert
struct CvPack {
  const void* src[9];
  bf16_t* dst[9];
  int n[9];
};

__global__ __launch_bounds__(256) void convert_all_k(CvPack p, const int* __restrict__ flag) {
  const int which = blockIdx.y;
  const int n = p.n[which];
  const int f32 = *flag;
  const int stride = gridDim.x * 256 * 8;
  for (int i = (blockIdx.x * 256 + threadIdx.x) * 8; i < n; i += stride) {
    if (f32) {
      const float* s = (const float*)p.src[which] + i;
      f32x4 lo = *(const f32x4*)s;
      f32x4 hi = *(const f32x4*)(s + 4);
      bf16x8 v;
#pragma unroll
      for (int j = 0; j < 4; ++j) { v[j] = (bf16_t)lo[j]; v[j + 4] = (bf16_t)hi[j]; }
      *(bf16x8*)(p.dst[which] + i) = v;
    } else {
      *(bf16x8*)(p.dst[which] + i) = *(const bf16x8*)((const bf16_t*)p.src[which] + i);
    }
  }
}

// ---------------------------------------------------------------- transpose (dtype-flex in)
__global__ void transpose_k(const void* __restrict__ in, bf16_t* __restrict__ out,
                            int R, int C, const int* __restrict__ flag) {
  __shared__ bf16_t tile[32][33];
  const int f32 = *flag;
  int bx = blockIdx.x * 32, by = blockIdx.y * 32;
  int tx = threadIdx.x, ty = threadIdx.y;
  for (int i = ty; i < 32; i += 8) {
    int r = by + i, c = bx + tx;
    if (r < R && c < C) {
      size_t idx = (size_t)r * C + c;
      tile[i][tx] = f32 ? (bf16_t)((const float*)in)[idx] : ((const bf16_t*)in)[idx];
    }
  }
  __syncthreads();
  for (int i = ty; i < 32; i += 8) {
    int r = bx + i, c = by + tx;  // out[r][c] = in[c][r]
    if (r < C && c < R) out[(size_t)r * R + c] = tile[tx][i];
  }
}

// ---------------------------------------------------------------- GEMM  C = A @ B^T (bf16)
#define BM 128
#define BN 128
#define BK 32
#define APITCH 40

__global__ __launch_bounds__(256) void gemm_nt(const bf16_t* __restrict__ A,
                                               const bf16_t* __restrict__ B,
                                               bf16_t* __restrict__ Cm,
                                               int M, int N, int K,
                                               int lda, int ldb, int ldc) {
  __shared__ bf16_t As[BM * APITCH];
  __shared__ bf16_t Bs[BN * APITCH];
  const int tid = threadIdx.x;
  const int lane = tid & 63;
  const int wave = tid >> 6;
  const int l16 = lane & 15, quad = lane >> 4;
  const int bm = blockIdx.x * BM, bn = blockIdx.y * BN;
  const int wm = (wave >> 1) * 64, wn = (wave & 1) * 64;
  f32x4 acc[4][4] = {};

  for (int k0 = 0; k0 < K; k0 += BK) {
    __syncthreads();
#pragma unroll
    for (int r = 0; r < 2; ++r) {
      int idx = r * 256 + tid;
      int row = idx >> 2;
      int col = (idx & 3) * 8;
      int ar = bm + row; if (ar > M - 1) ar = M - 1;
      bf16x8 va = *(const bf16x8*)(A + (size_t)ar * lda + k0 + col);
      *(bf16x8*)(As + row * APITCH + col) = va;
      int br = bn + row; if (br > N - 1) br = N - 1;
      bf16x8 vb = *(const bf16x8*)(B + (size_t)br * ldb + k0 + col);
      *(bf16x8*)(Bs + row * APITCH + col) = vb;
    }
    __syncthreads();
    bf16x8 af[4], bfr[4];
#pragma unroll
    for (int i = 0; i < 4; ++i)
      af[i] = *(const bf16x8*)(As + (wm + i * 16 + l16) * APITCH + quad * 8);
#pragma unroll
    for (int j = 0; j < 4; ++j)
      bfr[j] = *(const bf16x8*)(Bs + (wn + j * 16 + l16) * APITCH + quad * 8);
#pragma unroll
    for (int i = 0; i < 4; ++i)
#pragma unroll
      for (int j = 0; j < 4; ++j)
        acc[i][j] = __builtin_amdgcn_mfma_f32_16x16x32_bf16(af[i], bfr[j], acc[i][j], 0, 0, 0);
  }
#pragma unroll
  for (int i = 0; i < 4; ++i)
#pragma unroll
    for (int j = 0; j < 4; ++j)
#pragma unroll
      for (int r = 0; r < 4; ++r) {
        int gm = bm + wm + i * 16 + quad * 4 + r;
        int gn = bn + wn + j * 16 + l16;
        if (gm < M && gn < N) Cm[(size_t)gm * ldc + gn] = (bf16_t)acc[i][j][r];
      }
}

// ---------------------------------------------------------------- pack + rope
// qcat: (T, 3072) = [q_up (cols 0..2047) | q_r (cols 2048..3071)]
__global__ void pack_q_k(const bf16_t* __restrict__ qcat,
                         const bf16_t* __restrict__ fc, const bf16_t* __restrict__ fs,
                         bf16_t* __restrict__ Qp) {
  int idx = blockIdx.x * blockDim.x + threadIdx.x;
  if (idx >= NH * T_DIM * 96) return;
  int j = idx % 96;
  int t = (idx / 96) % T_DIM;
  int h = idx / (96 * T_DIM);
  const float scale = 0.07216878364870323f;  // 1/sqrt(HS+DHR)
  bf16_t* out = Qp + ((size_t)h * T_DIM + t) * QKD;
  if (j < 64) {
    float a = (float)qcat[(size_t)t * 3072 + h * HS + 2 * j];
    float b = (float)qcat[(size_t)t * 3072 + h * HS + 2 * j + 1];
    out[2 * j] = (bf16_t)(a * scale);
    out[2 * j + 1] = (bf16_t)(b * scale);
  } else {
    int i = j - 64;
    float re = (float)qcat[(size_t)t * 3072 + 2048 + h * DHR + 2 * i];
    float im = (float)qcat[(size_t)t * 3072 + 2048 + h * DHR + 2 * i + 1];
    float c = (float)fc[t * 32 + i], s = (float)fs[t * 32 + i];
    out[HS + 2 * i] = (bf16_t)((re * c - im * s) * scale);
    out[HS + 2 * i + 1] = (bf16_t)((re * s + im * c) * scale);
  }
}

// khead: (T, 2048); k_r lives in xa cols 2048..2111 (ld 2112)
__global__ void pack_k_k(const bf16_t* __restrict__ khead, const bf16_t* __restrict__ xa,
                         const bf16_t* __restrict__ fc, const bf16_t* __restrict__ fs,
                         bf16_t* __restrict__ Kp) {
  int idx = blockIdx.x * blockDim.x + threadIdx.x;
  if (idx >= NH * T_DIM * 96) return;
  int j = idx % 96;
  int t = (idx / 96) % T_DIM;
  int h = idx / (96 * T_DIM);
  bf16_t* out = Kp + ((size_t)h * T_DIM + t) * QKD;
  if (j < 64) {
    out[2 * j] = khead[(size_t)t * C_DIM + h * HS + 2 * j];
    out[2 * j + 1] = khead[(size_t)t * C_DIM + h * HS + 2 * j + 1];
  } else {
    int i = j - 64;
    float re = (float)xa[(size_t)t * 2112 + 2048 + 2 * i];
    float im = (float)xa[(size_t)t * 2112 + 2048 + 2 * i + 1];
    float c = (float)fc[t * 32 + i], s = (float)fs[t * 32 + i];
    out[HS + 2 * i] = (bf16_t)(re * c - im * s);
    out[HS + 2 * i + 1] = (bf16_t)(re * s + im * c);
  }
}

// ---------------------------------------------------------------- flash attention
// VT pre-transposed: VT[h*HS + d][t]  (row stride T_DIM)
#define FBM 64
#define FBN 64
#define KPITCH 200
#define VPITCH 72
#define PPITCH 72

__global__ __launch_bounds__(256) void flash_k(const bf16_t* __restrict__ Qp,
                                               const bf16_t* __restrict__ Kp,
                                               const bf16_t* __restrict__ VT,
                                               void* __restrict__ Y,
                                               const int* __restrict__ flag) {
  __shared__ bf16_t Ksm[FBN * KPITCH];
  __shared__ bf16_t Vtsm[HS * VPITCH];
  __shared__ bf16_t Psm[4][16 * PPITCH];
  const int tid = threadIdx.x;
  const int lane = tid & 63, wave = tid >> 6;
  const int l16 = lane & 15, quad = lane >> 4;
  const int h = blockIdx.y;
  const int qtile = (gridDim.x - 1) - blockIdx.x;  // longest-first dispatch
  const int qb = qtile * FBM;
  const int f32out = *flag;

  bf16x8 aq[6];
  const bf16_t* qbase = Qp + ((size_t)h * T_DIM + qb + wave * 16 + l16) * QKD;
#pragma unroll
  for (int c = 0; c < 6; ++c) aq[c] = *(const bf16x8*)(qbase + c * 32 + quad * 8);

  f32x4 o[8] = {};
  float m_i[4], l_i[4];
#pragma unroll
  for (int r = 0; r < 4; ++r) { m_i[r] = -3.0e38f; l_i[r] = 0.f; }

  const bf16_t* kg_base = Kp + (size_t)h * T_DIM * QKD;
  const bf16_t* vg_base = VT + (size_t)(h * HS) * T_DIM;

  // register prefetch buffers (software pipeline: load kt+1 during compute of kt)
  bf16x8 kreg[6], vreg[4];
#pragma unroll
  for (int i = 0; i < 6; ++i) {
    int idx = i * 256 + tid, row = idx / 24, c8 = idx % 24;
    kreg[i] = *(const bf16x8*)(kg_base + (size_t)row * QKD + c8 * 8);
  }
#pragma unroll
  for (int i = 0; i < 4; ++i) {
    int idx = i * 256 + tid, row = idx >> 3, c8 = idx & 7;
    vreg[i] = *(const bf16x8*)(vg_base + (size_t)row * T_DIM + c8 * 8);
  }

  for (int kt = 0; kt <= qtile; ++kt) {
    __syncthreads();  // previous compute done -> LDS writable
#pragma unroll
    for (int i = 0; i < 6; ++i) {
      int idx = i * 256 + tid, row = idx / 24, c8 = idx % 24;
      *(bf16x8*)(Ksm + row * KPITCH + c8 * 8) = kreg[i];
    }
#pragma unroll
    for (int i = 0; i < 4; ++i) {
      int idx = i * 256 + tid, row = idx >> 3, c8 = idx & 7;
      *(bf16x8*)(Vtsm + row * VPITCH + c8 * 8) = vreg[i];
    }
    __syncthreads();  // LDS ready
    if (kt < qtile) {
      const bf16_t* kg = kg_base + (size_t)(kt + 1) * FBN * QKD;
#pragma unroll
      for (int i = 0; i < 6; ++i) {
        int idx = i * 256 + tid, row = idx / 24, c8 = idx % 24;
        kreg[i] = *(const bf16x8*)(kg + (size_t)row * QKD + c8 * 8);
      }
      const bf16_t* vg = vg_base + (kt + 1) * FBN;
#pragma unroll
      for (int i = 0; i < 4; ++i) {
        int idx = i * 256 + tid, row = idx >> 3, c8 = idx & 7;
        vreg[i] = *(const bf16x8*)(vg + (size_t)row * T_DIM + c8 * 8);
      }
    }
    // S = Q @ K^T
    f32x4 sc[4] = {};
#pragma unroll
    for (int nt = 0; nt < 4; ++nt)
#pragma unroll
      for (int c = 0; c < 6; ++c) {
        bf16x8 bk = *(const bf16x8*)(Ksm + (nt * 16 + l16) * KPITCH + c * 32 + quad * 8);
        sc[nt] = __builtin_amdgcn_mfma_f32_16x16x32_bf16(aq[c], bk, sc[nt], 0, 0, 0);
      }
    if (kt == qtile) {
#pragma unroll
      for (int nt = 0; nt < 4; ++nt) {
        int s_loc = nt * 16 + l16;
#pragma unroll
        for (int r = 0; r < 4; ++r) {
          int t_loc = wave * 16 + quad * 4 + r;
          if (s_loc > t_loc) sc[nt][r] = -3.0e38f;
        }
      }
    }
    // online softmax
    float p[4][4];
#pragma unroll
    for (int r = 0; r < 4; ++r) {
      float mx = fmaxf(fmaxf(sc[0][r], sc[1][r]), fmaxf(sc[2][r], sc[3][r]));
#pragma unroll
      for (int m = 1; m < 16; m <<= 1) mx = fmaxf(mx, __shfl_xor(mx, m, 64));
      float mn = fmaxf(m_i[r], mx);
      float alpha = exp2f((m_i[r] - mn) * 1.4426950408889634f);
      float rs = 0.f;
#pragma unroll
      for (int nt = 0; nt < 4; ++nt) {
        float pv = exp2f((sc[nt][r] - mn) * 1.4426950408889634f);
        p[nt][r] = pv;
        rs += pv;
      }
#pragma unroll
      for (int m = 1; m < 16; m <<= 1) rs += __shfl_xor(rs, m, 64);
      l_i[r] = l_i[r] * alpha + rs;
      m_i[r] = mn;
#pragma unroll
      for (int dt = 0; dt < 8; ++dt) o[dt][r] *= alpha;
    }
    // P: C-layout -> LDS -> A-operand layout (per-wave buffer, no barrier)
#pragma unroll
    for (int nt = 0; nt < 4; ++nt)
#pragma unroll
      for (int r = 0; r < 4; ++r)
        Psm[wave][(quad * 4 + r) * PPITCH + nt * 16 + l16] = (bf16_t)p[nt][r];
#pragma unroll
    for (int s2 = 0; s2 < 2; ++s2) {
      bf16x8 ap = *(const bf16x8*)(&Psm[wave][l16 * PPITCH + s2 * 32 + quad * 8]);
#pragma unroll
      for (int dt = 0; dt < 8; ++dt) {
        bf16x8 bv = *(const bf16x8*)(Vtsm + (dt * 16 + l16) * VPITCH + s2 * 32 + quad * 8);
        o[dt] = __builtin_amdgcn_mfma_f32_16x16x32_bf16(ap, bv, o[dt], 0, 0, 0);
      }
    }
  }
#pragma unroll
  for (int r = 0; r < 4; ++r) {
    float inv = 1.0f / l_i[r];
    int t = qb + wave * 16 + quad * 4 + r;
#pragma unroll
    for (int dt = 0; dt < 8; ++dt) {
      size_t oi = (size_t)t * C_DIM + h * HS + dt * 16 + l16;
      float val = o[dt][r] * inv;
      if (f32out) ((float*)Y)[oi] = val;
      else        ((bf16_t*)Y)[oi] = (bf16_t)val;
    }
  }
}

// ---------------------------------------------------------------- launch
extern "C" void kernel_launch(void* const* d_in, const int* in_sizes, int n_in,
                              void* d_out, int out_size, void* d_ws, size_t ws_size,
                              hipStream_t stream) {
  bf16_t* w = (bf16_t*)d_ws;
  int* flag = (int*)d_ws;  // first 4 bytes; buffers start at element 64

  if (ws_size < (size_t)34472000 * 2 + 128) return;

  // ---- workspace layout (bf16 elements), lifetime-aliased ----
  bf16_t* fcc    = w + 64;        // 65536
  bf16_t* fsc    = w + 65600;     // 65536
  bf16_t* xc     = w + 131136;    // 4194304
  bf16_t* BigB   = w + 4325440;   // 4325376 = [W_dq(1536) | W_dkv(512) | W_kr(64)] x 2048
  bf16_t* dqc    = BigB;
  bf16_t* dkvc   = BigB + 3145728;
  bf16_t* krc    = BigB + 4194304;
  bf16_t* Bq     = w + 8650816;   // 4718592 = [W_uq_t(2048) | W_qr(1024)] x 1536
  bf16_t* W_uq_t = Bq;
  bf16_t* qrc    = Bq + 3145728;
  bf16_t* xa     = w + 13369408;  // 4325376: cols [c_q(1536) | c_kv(512) | k_r(64)], ld 2112
  bf16_t* qcat   = w + 17694784;  // 6291456: cols [q_up(2048) | q_r(1024)], ld 3072
  bf16_t* k_head = w + 23986240;  // 4194304
  bf16_t* vhatT  = w + 28180544;  // 4194304
  bf16_t* ukc    = w + 32374848;  // 1048576
  bf16_t* Pt     = w + 33423424;  // 1048576
  // aliases (lifetime-disjoint, verified by launch order below)
  bf16_t* woc    = qcat;          // W_o bf16; dead before qcat GEMM writes here
  bf16_t* W_uv_t = k_head;        // dead before k_head GEMM writes here
  bf16_t* Qpack  = xc;            // 6291456 over xc+BigB; both dead after xa GEMM
  bf16_t* Kpack  = qcat;          // qcat dead after pack_q_k

  detect_k<<<1, 64, 0, stream>>>((const bf16_t*)d_in[0], flag);

  CvPack cp;
  const void* srcs[9] = {d_in[1], d_in[2], d_in[0], d_in[3], d_in[5], d_in[9], d_in[8], d_in[6], d_in[10]};
  bf16_t* dsts[9]     = {fcc,     fsc,     xc,      dqc,     dkvc,    krc,     qrc,     ukc,     woc};
  int ns[9] = {T_DIM * 32, T_DIM * 32, T_DIM * C_DIM, NLQ * C_DIM, NLKV * C_DIM,
               DHR * C_DIM, NH * DHR * NLQ, C_DIM * NLKV, C_DIM * C_DIM};
  for (int i = 0; i < 9; ++i) { cp.src[i] = srcs[i]; cp.dst[i] = dsts[i]; cp.n[i] = ns[i]; }
  convert_all_k<<<dim3(512, 9), 256, 0, stream>>>(cp, flag);

  dim3 tb(32, 8);
  // W_uq flat (1536,2048) -> W_uq_t (2048,1536)
  transpose_k<<<dim3(64, 48), tb, 0, stream>>>(d_in[4], W_uq_t, 1536, 2048, flag);
  // W_uv (2048,512) -> W_uv_t (512,2048)
  transpose_k<<<dim3(16, 64), tb, 0, stream>>>(d_in[7], W_uv_t, 2048, 512, flag);

  // Pt = W_o @ W_uv            (2048,512,K=2048)  [early: frees woc, W_uv_t]
  gemm_nt<<<dim3(16, 4), 256, 0, stream>>>(woc, W_uv_t, Pt, 2048, 512, 2048, 2048, 2048, 512);
  // xa = x @ [W_dq;W_dkv;W_kr]^T   (2048,2112,K=2048)
  gemm_nt<<<dim3(16, 17), 256, 0, stream>>>(xc, BigB, xa, 2048, 2112, 2048, 2048, 2048, 2112);
  // qcat = c_q @ [W_uq_t;W_qr]^T   (2048,3072,K=1536)
  gemm_nt<<<dim3(16, 24), 256, 0, stream>>>(xa, Bq, qcat, 2048, 3072, 1536, 2112, 1536, 3072);
  // k_head = c_kv @ W_uk^T     (2048,2048,K=512)
  gemm_nt<<<dim3(16, 16), 256, 0, stream>>>(xa + 1536, ukc, k_head, 2048, 2048, 512, 2112, 512, 2048);
  // vhatT = Pt @ c_kv^T        (2048,2048,K=512)
  gemm_nt<<<dim3(16, 16), 256, 0, stream>>>(Pt, xa + 1536, vhatT, 2048, 2048, 512, 512, 2112, 2048);

  int pk = (NH * T_DIM * 96 + 255) / 256;
  pack_q_k<<<pk, 256, 0, stream>>>(qcat, fcc, fsc, Qpack);
  pack_k_k<<<pk, 256, 0, stream>>>(k_head, xa, fcc, fsc, Kpack);

  flash_k<<<dim3(T_DIM / FBM, NH), 256, 0, stream>>>(Qpack, Kpack, vhatT, d_out, flag);
}